// Round 5
// baseline (143.391 us; speedup 1.0000x reference)
//
#include <hip/hip_runtime.h>
#include <hip/hip_bf16.h>
#include <cstdint>

// Problem dims (fixed by reference)
#define B_  16
#define N_  32
#define L_  2048
#define D_  16
#define M_  32
#define K_  3
#define W_  2046   // (L - K)/STRIDE + 1

typedef __bf16 bf16x8 __attribute__((ext_vector_type(8)));
typedef float  f32x4  __attribute__((ext_vector_type(4)));

union frag_cast { uint4 u; bf16x8 f; };

// pack two fp32 -> one u32 holding two RTNE bf16 (a in low half)
__device__ __forceinline__ uint32_t pk2(float a, float b) {
    __hip_bfloat162 p = __float22bfloat162_rn(make_float2(a, b));
    union { __hip_bfloat162 h; uint32_t u; } cv; cv.h = p; return cv.u;
}

// async 16-B global->LDS (direct-to-shared DMA; LDS dest = base + lane*16)
__device__ __forceinline__ void gload_lds16(const uint4* g, void* l) {
    __builtin_amdgcn_global_load_lds(
        (const __attribute__((address_space(1))) unsigned int*)g,
        (__attribute__((address_space(3))) unsigned int*)l, 16, 0, 0);
}

// ---------------------------------------------------------------------------
// Pass A: x [B][N][L][16] f32  ->  xbf granules, granule(b,n2,l,a) = 16 B
//   = bf16{ x[b,2n2,l,4a..4a+3], x[b,2n2+1,l,4a..4a+3] }
// laid out [b][n2][l][a] (same content as the VERIFIED LDS granules).
// Granule id g = ((b*16+n2)*2048 + l)*4 + a; even-row float4 idx = g + (g>>13)*8192.
// Per instruction: 64 lanes read/write 1 KB contiguous.  Pure streamer.
// ---------------------------------------------------------------------------
__global__ __launch_bounds__(256) void caps_xcvt(const float* __restrict__ xp,
                                                 uint4* __restrict__ xbf) {
    const int lane = threadIdx.x & 63, wv = threadIdx.x >> 6;
    const int base = (blockIdx.x * 4 + wv) * 256 + lane;   // granule id base
    const float4* xf4 = (const float4*)xp;
    float4 e[4], o[4];
#pragma unroll
    for (int j = 0; j < 4; ++j) {
        const int g = base + 64 * j;
        const size_t fE = (size_t)g + (size_t)(g >> 13) * 8192;
        e[j] = xf4[fE];          // n = 2*n2
        o[j] = xf4[fE + 8192];   // n = 2*n2+1
    }
#pragma unroll
    for (int j = 0; j < 4; ++j) {
        const int g = base + 64 * j;
        uint4 u;
        u.x = pk2(e[j].x, e[j].y); u.y = pk2(e[j].z, e[j].w);
        u.z = pk2(o[j].x, o[j].y); u.w = pk2(o[j].z, o[j].w);
        xbf[g] = u;
    }
}

// ---------------------------------------------------------------------------
// Setup: transpose + scale weights into MFMA B-fragment order.
// (ROUND-3/5 VERIFIED MAPPING — values unchanged; now lives at ws+XBF.)
// ---------------------------------------------------------------------------
__global__ __launch_bounds__(64) void caps_setup(const float* __restrict__ wp,
                                                 uint2* __restrict__ ws2) {
    const int gid  = blockIdx.x * 64 + threadIdx.x;   // 0..12287
    const int i    = gid >> 1;                        // uint4 index 0..6143
    const int half = gid & 1;
    const int ct   = i / 768;
    const int rem  = i - ct * 768;
    const int kc   = rem >> 6;
    const int lane = rem & 63;
    const int q    = lane >> 4;
    const int col  = (ct << 4) | (lane & 15);
    const int m = col >> 2, d = col & 3;
    const int k = kc >> 2;
    const int n = (kc & 3) * 8 + q * 2 + half;
    float f[4];
#pragma unroll
    for (int x = 0; x < 4; ++x)
        f[x] = wp[(((k * 32 + n) * 4 + x) * 4 + d) * 32 + m] * 0.03125f;
    uint2 o;
    o.x = pk2(f[0], f[1]); o.y = pk2(f[2], f[3]);
    ws2[i * 2 + half] = o;
}

// x LDS tile layout (per slab buffer, VERIFIED): byte = n2*1184 + w*64 + a*16.
// Buffer padded to 19456 B = 19 chunks of 1024 B for linear global_load_lds.
#define XSTRIDE_N2 1184
#define XDATA_BYTES (16 * XSTRIDE_N2)   // 18944 B of real data
#define XBUF 19456                      // padded buffer (19 x 1024)
#define XCHUNK 19

#define XBF_U4 (16 * 2048 * 4)          // granules per b
#define XBF_BYTES (16 * 16 * 2048 * 4 * 16)  // 33,554,432

// ---------------------------------------------------------------------------
// R10: async two-pass.  Staging = 19 global_load_lds chunks per slab (no regs,
// no VALU, no ds_write); prefetch of slab s+1 issues before slab s K-loop and
// is drained by the existing end-of-slab __syncthreads.  K-loop + LN mapping
// byte-identical to R3/R5-VERIFIED.  Stores: 4x4 quad-lane transpose ->
// one dwordx4 per (rt,cp) instead of 4 strided dwords.
// Grid (64,16), 2 slabs x 16 w; breg[2][12] persistent.
// ---------------------------------------------------------------------------
__global__ __launch_bounds__(256, 2) void caps_mfma(
    const uint4* __restrict__ xbf,  // pre-packed granules [b][n2][l][a]
    const uint4* __restrict__ ws,   // B frags
    const float* __restrict__ gp,   // [16]
    const float* __restrict__ bp,   // [16]
    float* __restrict__ out)        // [B][M][W][16]
{
    __shared__ __align__(16) unsigned char xs[2 * XBUF];

    const int tid  = threadIdx.x;
    const int wave = tid >> 6;
    const int lane = tid & 63;
    const int q    = lane >> 4;
    const int l15  = lane & 15;
    const int dL   = lane & 3;
    const int msub = (lane >> 2) & 3;
    const int b    = blockIdx.y;
    const int W0   = blockIdx.x * 32;  // 32-w super-tile (2 slabs x 16)
    const int ct0  = wave * 2;

    const uint4* xb = xbf + (size_t)b * XBF_U4;

    // ---- chunk geometry (prologue, slab-independent).  Chunk ch = 4i+wave,
    // dest byte = ch*1024 + lane*16 -> (n2, w, a); pad lanes clamped to a
    // safe duplicate source (their LDS bytes are never read). ----
    int  srcb[5];   // granule index n2*8192 + a  (+ gw*4 per slab)
    int  wrow[5];
    int  lofs[5];
    bool cval[5];
#pragma unroll
    for (int i = 0; i < 5; ++i) {
        const int ch = 4 * i + wave;
        cval[i] = ch < XCHUNK;
        const int dest = ch * 1024 + lane * 16;
        int n2  = dest / XSTRIDE_N2;
        int rem = dest - n2 * XSTRIDE_N2;
        int w   = rem >> 6;
        int a   = (rem >> 4) & 3;
        if (n2 > 15) { n2 = 15; w = 17; a = 3; }   // buffer-end pad
        if (w > 17)  { w = 17; }                   // per-n2 32-B pad
        srcb[i] = n2 * 8192 + a;
        wrow[i] = w;
        lofs[i] = dest;
    }

    auto issue = [&](int s, int buf) {
#pragma unroll
        for (int i = 0; i < 5; ++i) if (cval[i]) {
            int gw = W0 + s * 16 + wrow[i];
            if (gw > L_ - 1) gw = L_ - 1;          // halo clamp
            gload_lds16(xb + srcb[i] + gw * 4, &xs[buf + lofs[i]]);
        }
    };

    // ---- prologue: async slab-0 stage + persistent B frags + gamma/beta ----
    issue(0, 0);

    uint4 breg[2][12];                             // 96 VGPR, block lifetime
#pragma unroll
    for (int cp = 0; cp < 2; ++cp)
#pragma unroll
        for (int kc = 0; kc < 12; ++kc)
            breg[cp][kc] = ws[(ct0 + cp) * 768 + kc * 64 + lane];

    float gmv[4], btv[4];
#pragma unroll
    for (int r = 0; r < 4; ++r) { gmv[r] = gp[r * 4 + dL]; btv[r] = bp[r * 4 + dL]; }

    __syncthreads();   // drains vmcnt -> slab-0 LDS image complete

    const unsigned char* ap =
        &xs[q * XSTRIDE_N2 + (l15 >> 2) * 64 + (l15 & 3) * 16];

#pragma unroll
    for (int s = 0; s < 2; ++s) {
        const int cur = s * XBUF;

        if (s < 1) issue(1, XBUF);                 // async prefetch slab 1
        __builtin_amdgcn_sched_barrier(0);         // pin issue before K-loop

        f32x4 acc[4][2];
#pragma unroll
        for (int rt = 0; rt < 4; ++rt)
#pragma unroll
            for (int cp = 0; cp < 2; ++cp)
                acc[rt][cp] = (f32x4){0.f, 0.f, 0.f, 0.f};

        // ---- K-loop: pure LDS + MFMA (VERIFIED layout/immediates) ----
#pragma unroll
        for (int kc = 0; kc < 12; ++kc) {
            const int k  = kc >> 2;
            const int kn = kc & 3;
            bf16x8 afr[4];
#pragma unroll
            for (int rt = 0; rt < 4; ++rt) {
                frag_cast c;
                c.u = *reinterpret_cast<const uint4*>(
                    ap + cur + kn * 4736 + k * 64 + rt * 256);
                afr[rt] = c.f;
            }
#pragma unroll
            for (int cp = 0; cp < 2; ++cp) {
                frag_cast bc; bc.u = breg[cp][kc];
#pragma unroll
                for (int rt = 0; rt < 4; ++rt)
                    acc[rt][cp] = __builtin_amdgcn_mfma_f32_16x16x32_bf16(
                        afr[rt], bc.f, acc[rt][cp], 0, 0, 0);
            }
        }

        // ---- fused LayerNorm (VERIFIED) + 4x4 quad transpose + dwordx4 ----
#pragma unroll
        for (int rt = 0; rt < 4; ++rt) {
            const int wv = W0 + s * 16 + rt * 4 + q;
#pragma unroll
            for (int cp = 0; cp < 2; ++cp) {
                const f32x4 v = acc[rt][cp];
                float ss = v[0] + v[1] + v[2] + v[3];
                float sq = v[0]*v[0] + v[1]*v[1] + v[2]*v[2] + v[3]*v[3];
                ss += __shfl_xor(ss, 1); ss += __shfl_xor(ss, 2);
                sq += __shfl_xor(sq, 1); sq += __shfl_xor(sq, 2);
                const float mu   = ss * (1.f / 16.f);
                const float var  = sq * (1.f / 16.f) - mu * mu;
                const float rstd = rsqrtf(var + 1e-5f);
                float y[4];
#pragma unroll
                for (int r = 0; r < 4; ++r)
                    y[r] = gmv[r] * (v[r] - mu) * rstd + btv[r];
                // 4x4 transpose over (dL, r): final(t,i) = old(i,t)
                // -> lane dL holds dout = 4*dL .. 4*dL+3 contiguous.
#pragma unroll
                for (int mm = 1; mm <= 2; mm <<= 1) {
                    float p[4];
#pragma unroll
                    for (int r = 0; r < 4; ++r) p[r] = __shfl_xor(y[r], mm);
#pragma unroll
                    for (int r = 0; r < 4; ++r)
                        y[r] = ((dL ^ r) & mm) ? p[r ^ mm] : y[r];
                }
                if (wv < W_) {
                    const int m = (ct0 + cp) * 4 + msub;
                    float4* op = (float4*)(out +
                        ((size_t)(b * M_ + m) * W_ + wv) * D_ + dL * 4);
                    *op = make_float4(y[0], y[1], y[2], y[3]);
                }
            }
        }

        if (s < 1) __syncthreads();  // drains own vmcnt -> slab-1 image ready
    }
}

extern "C" void kernel_launch(void* const* d_in, const int* in_sizes, int n_in,
                              void* d_out, int out_size, void* d_ws, size_t ws_size,
                              hipStream_t stream) {
    const float* x  = (const float*)d_in[0];
    const float* w  = (const float*)d_in[1];
    const float* g  = (const float*)d_in[2];
    const float* be = (const float*)d_in[3];
    float* out = (float*)d_out;

    uint4* xbf = (uint4*)d_ws;
    uint2* wsB = (uint2*)((char*)d_ws + XBF_BYTES);

    caps_xcvt<<<2048, 256, 0, stream>>>(x, xbf);
    caps_setup<<<192, 64, 0, stream>>>(w, wsB);
    caps_mfma<<<dim3(64, 16), 256, 0, stream>>>(
        xbf, (const uint4*)((char*)d_ws + XBF_BYTES), g, be, out);
}

// Round 6
// 137.929 us; speedup vs baseline: 1.0396x; 1.0396x over previous
//
#include <hip/hip_runtime.h>
#include <hip/hip_bf16.h>
#include <cstdint>

// Problem dims (fixed by reference)
#define B_  16
#define N_  32
#define L_  2048
#define D_  16
#define M_  32
#define K_  3
#define W_  2046   // (L - K)/STRIDE + 1

typedef __bf16 bf16x8 __attribute__((ext_vector_type(8)));
typedef float  f32x4  __attribute__((ext_vector_type(4)));

union frag_cast { uint4 u; bf16x8 f; };

// pack two fp32 -> one u32 holding two RTNE bf16 (a in low half)
__device__ __forceinline__ uint32_t pk2(float a, float b) {
    __hip_bfloat162 p = __float22bfloat162_rn(make_float2(a, b));
    union { __hip_bfloat162 h; uint32_t u; } cv; cv.h = p; return cv.u;
}

// async 16-B global->LDS (direct-to-shared DMA; linear dest, per-lane src)
__device__ __forceinline__ void gload_lds16(const uint4* g, void* l) {
    __builtin_amdgcn_global_load_lds(
        (const __attribute__((address_space(1))) unsigned int*)g,
        (__attribute__((address_space(3))) unsigned int*)l, 16, 0, 0);
}

// ---------------------------------------------------------------------------
// Setup: transpose + scale weights into MFMA B-fragment order in d_ws.
// (ROUND-3/5 VERIFIED MAPPING — values unchanged.)
// GEMM: K index κ = (k*32 + n)*4 + x  (k-major), col c = m*4 + d.
// ws layout: uint4[ct(8)][kc(12)][lane(64)]; lane's uint4 = 8 bf16 =
// B[κ = kc*32 + (lane>>4)*8 + j][col = ct*16 + (lane&15)], j = 0..7.
// ---------------------------------------------------------------------------
__global__ __launch_bounds__(64) void caps_setup(const float* __restrict__ wp,
                                                 uint2* __restrict__ ws2) {
    const int gid  = blockIdx.x * 64 + threadIdx.x;   // 0..12287
    const int i    = gid >> 1;                        // uint4 index 0..6143
    const int half = gid & 1;
    const int ct   = i / 768;
    const int rem  = i - ct * 768;
    const int kc   = rem >> 6;
    const int lane = rem & 63;
    const int q    = lane >> 4;
    const int col  = (ct << 4) | (lane & 15);
    const int m = col >> 2, d = col & 3;
    const int k = kc >> 2;
    const int n = (kc & 3) * 8 + q * 2 + half;
    float f[4];
#pragma unroll
    for (int x = 0; x < 4; ++x)
        f[x] = wp[(((k * 32 + n) * 4 + x) * 4 + d) * 32 + m] * 0.03125f;
    uint2 o;
    o.x = pk2(f[0], f[1]); o.y = pk2(f[2], f[3]);
    ws2[i * 2 + half] = o;
}

// f32 x LDS slab layout: byte(n,w,a) = n*1184 + w*64 + a*16
//   n = 0..31 input capsule, w = 0..17 window row, a = 0..3 (4 floats each).
// 32*1184 = 37888 B = EXACTLY 37 linear chunks of 1024 B for global_load_lds.
// Row tail bytes [1152,1184) per n are pad (w reads stop at 17).
#define XROW   1184
#define XBUF   37888
#define XCHUNK 37

// ---------------------------------------------------------------------------
// R11: ONE pass, async f32 staging + in-register bf16 conversion.
//  - staging: 37 global_load_lds chunks/slab (no regs, no VALU, async);
//    prefetch of slab s+1 issues before slab s K-loop, drained by the
//    end-of-slab __syncthreads.
//  - A-frag (VERIFIED mapping: rows n = 8kn+2q+{0,1}, w = (l15>>2)+k+4rt,
//    a = l15&3): two ds_read_b128 (even/odd row) + 4 pk2 -> bf16x8; pack
//    order identical to the verified bf16 granule {even 4, odd 4}.
//  - stores: R5-verified 4x4 quad-lane transpose -> one dwordx4 each.
// Grid (64,16), 256 thr, 2 slabs x 16 w; breg[2][12] persistent.
// LDS 2 x 37888 = 75776 -> 2 blocks/CU; launch_bounds(256,2) frees VGPR.
// ---------------------------------------------------------------------------
__global__ __launch_bounds__(256, 2) void caps_mfma(
    const float* __restrict__ xp,   // [B][N][L][16] f32
    const uint4* __restrict__ ws,   // B frags
    const float* __restrict__ gp,   // [16]
    const float* __restrict__ bp,   // [16]
    float* __restrict__ out)        // [B][M][W][16]
{
    __shared__ __align__(16) unsigned char xs[2 * XBUF];

    const int tid  = threadIdx.x;
    const int wave = tid >> 6;
    const int lane = tid & 63;
    const int q    = lane >> 4;
    const int l15  = lane & 15;
    const int dL   = lane & 3;
    const int msub = (lane >> 2) & 3;
    const int b    = blockIdx.y;
    const int W0   = blockIdx.x * 32;  // 32-w super-tile (2 slabs x 16)
    const int ct0  = wave * 2;

    const float* xb = xp + (size_t)b * N_ * L_ * D_;

    // ---- chunk geometry (slab-independent): ch = 4i+wave, 10 per wave ----
    int  srcf[10];   // float offset n*32768 + a*4 (gw*16 added per slab)
    int  wrow[10];
    int  lofs[10];
    bool cval[10];
#pragma unroll
    for (int i = 0; i < 10; ++i) {
        const int ch = 4 * i + wave;
        cval[i] = ch < XCHUNK;
        const int dest = ch * 1024 + lane * 16;
        int n   = dest / XROW;
        if (n > 31) n = 31;
        int rem = dest - n * XROW;
        int w   = rem >> 6;
        int a   = (rem >> 4) & 3;
        if (w > 17) { w = 17; }     // row-tail pad lanes: safe dup source
        srcf[i] = n * 32768 + a * 4;
        wrow[i] = w;
        lofs[i] = dest;
    }

    auto issue = [&](int s, int buf) {
#pragma unroll
        for (int i = 0; i < 10; ++i) if (cval[i]) {
            int gw = W0 + s * 16 + wrow[i];
            if (gw > L_ - 1) gw = L_ - 1;          // halo clamp
            gload_lds16((const uint4*)(xb + srcf[i] + gw * 16),
                        &xs[buf + lofs[i]]);
        }
    };

    // ---- prologue: async slab-0 stage + persistent B frags + gamma/beta ----
    issue(0, 0);

    uint4 breg[2][12];                             // 96 VGPR, block lifetime
#pragma unroll
    for (int cp = 0; cp < 2; ++cp)
#pragma unroll
        for (int kc = 0; kc < 12; ++kc)
            breg[cp][kc] = ws[(ct0 + cp) * 768 + kc * 64 + lane];

    float gmv[4], btv[4];
#pragma unroll
    for (int r = 0; r < 4; ++r) { gmv[r] = gp[r * 4 + dL]; btv[r] = bp[r * 4 + dL]; }

    __syncthreads();   // drains vmcnt -> slab-0 LDS image complete

    // per-lane A base (f32 layout): rows 2q, w = (l15>>2), a = l15&3
    const unsigned char* ap0 =
        &xs[q * 2 * XROW + (l15 >> 2) * 64 + (l15 & 3) * 16];

#pragma unroll
    for (int s = 0; s < 2; ++s) {
        const unsigned char* ap = ap0 + s * XBUF;

        if (s < 1) issue(1, XBUF);                 // async prefetch slab 1
        __builtin_amdgcn_sched_barrier(0);         // pin issue before K-loop

        f32x4 acc[4][2];
#pragma unroll
        for (int rt = 0; rt < 4; ++rt)
#pragma unroll
            for (int cp = 0; cp < 2; ++cp)
                acc[rt][cp] = (f32x4){0.f, 0.f, 0.f, 0.f};

        // ---- K-loop: ds_read f32 pair -> pk2 -> MFMA (VERIFIED mapping) ----
#pragma unroll
        for (int kc = 0; kc < 12; ++kc) {
            const int k  = kc >> 2;
            const int kn = kc & 3;
            bf16x8 afr[4];
#pragma unroll
            for (int rt = 0; rt < 4; ++rt) {
                const unsigned char* p =
                    ap + kn * (8 * XROW) + k * 64 + rt * 256;
                const f32x4 rE = *reinterpret_cast<const f32x4*>(p);         // n even
                const f32x4 rO = *reinterpret_cast<const f32x4*>(p + XROW);  // n odd
                frag_cast c;
                c.u.x = pk2(rE[0], rE[1]); c.u.y = pk2(rE[2], rE[3]);
                c.u.z = pk2(rO[0], rO[1]); c.u.w = pk2(rO[2], rO[3]);
                afr[rt] = c.f;
            }
#pragma unroll
            for (int cp = 0; cp < 2; ++cp) {
                frag_cast bc; bc.u = breg[cp][kc];
#pragma unroll
                for (int rt = 0; rt < 4; ++rt)
                    acc[rt][cp] = __builtin_amdgcn_mfma_f32_16x16x32_bf16(
                        afr[rt], bc.f, acc[rt][cp], 0, 0, 0);
            }
        }

        // ---- fused LayerNorm (VERIFIED) + 4x4 quad transpose + dwordx4 ----
#pragma unroll
        for (int rt = 0; rt < 4; ++rt) {
            const int wv = W0 + s * 16 + rt * 4 + q;
#pragma unroll
            for (int cp = 0; cp < 2; ++cp) {
                const f32x4 v = acc[rt][cp];
                float ss = v[0] + v[1] + v[2] + v[3];
                float sq = v[0]*v[0] + v[1]*v[1] + v[2]*v[2] + v[3]*v[3];
                ss += __shfl_xor(ss, 1); ss += __shfl_xor(ss, 2);
                sq += __shfl_xor(sq, 1); sq += __shfl_xor(sq, 2);
                const float mu   = ss * (1.f / 16.f);
                const float var  = sq * (1.f / 16.f) - mu * mu;
                const float rstd = rsqrtf(var + 1e-5f);
                float y[4];
#pragma unroll
                for (int r = 0; r < 4; ++r)
                    y[r] = gmv[r] * (v[r] - mu) * rstd + btv[r];
                // 4x4 transpose over (dL, r): lane dL -> dout 4dL..4dL+3
#pragma unroll
                for (int mm = 1; mm <= 2; mm <<= 1) {
                    float p[4];
#pragma unroll
                    for (int r = 0; r < 4; ++r) p[r] = __shfl_xor(y[r], mm);
#pragma unroll
                    for (int r = 0; r < 4; ++r)
                        y[r] = ((dL ^ r) & mm) ? p[r ^ mm] : y[r];
                }
                if (wv < W_) {
                    const int m = (ct0 + cp) * 4 + msub;
                    float4* op = (float4*)(out +
                        ((size_t)(b * M_ + m) * W_ + wv) * D_ + dL * 4);
                    *op = make_float4(y[0], y[1], y[2], y[3]);
                }
            }
        }

        if (s < 1) __syncthreads();  // drains own vmcnt -> slab-1 image ready
    }
}

extern "C" void kernel_launch(void* const* d_in, const int* in_sizes, int n_in,
                              void* d_out, int out_size, void* d_ws, size_t ws_size,
                              hipStream_t stream) {
    const float* x  = (const float*)d_in[0];
    const float* w  = (const float*)d_in[1];
    const float* g  = (const float*)d_in[2];
    const float* be = (const float*)d_in[3];
    float* out = (float*)d_out;

    caps_setup<<<192, 64, 0, stream>>>(w, (uint2*)d_ws);
    caps_mfma<<<dim3(64, 16), 256, 0, stream>>>(
        x, (const uint4*)d_ws, g, be, out);
}

// Round 7
// 134.453 us; speedup vs baseline: 1.0665x; 1.0259x over previous
//
#include <hip/hip_runtime.h>
#include <hip/hip_bf16.h>
#include <cstdint>

// Problem dims (fixed by reference)
#define B_  16
#define N_  32
#define L_  2048
#define D_  16
#define M_  32
#define K_  3
#define W_  2046   // (L - K)/STRIDE + 1

typedef __bf16 bf16x8 __attribute__((ext_vector_type(8)));
typedef float  f32x4  __attribute__((ext_vector_type(4)));

union frag_cast { uint4 u; bf16x8 f; };

// pack two fp32 -> one u32 holding two RTNE bf16 (a in low half)
__device__ __forceinline__ uint32_t pk2(float a, float b) {
    __hip_bfloat162 p = __float22bfloat162_rn(make_float2(a, b));
    union { __hip_bfloat162 h; uint32_t u; } cv; cv.h = p; return cv.u;
}

// async 16-B global->LDS (direct-to-shared DMA; wave-uniform dest + lane*16,
// per-lane source — verified pattern from R10/R11)
__device__ __forceinline__ void gload_lds16(const float* g, void* l) {
    __builtin_amdgcn_global_load_lds(
        (const __attribute__((address_space(1))) unsigned int*)g,
        (__attribute__((address_space(3))) unsigned int*)l, 16, 0, 0);
}

// ---------------------------------------------------------------------------
// Setup: transpose + scale weights into MFMA B-fragment order in d_ws.
// (ROUND-3/5 VERIFIED MAPPING — values unchanged.)
// ws layout: uint4[ct(8)][kc(12)][lane(64)]; lane's uint4 = 8 bf16 =
// B[κ = kc*32 + (lane>>4)*8 + j][col = ct*16 + (lane&15)], j = 0..7.
// ---------------------------------------------------------------------------
__global__ __launch_bounds__(64) void caps_setup(const float* __restrict__ wp,
                                                 uint2* __restrict__ ws2) {
    const int gid  = blockIdx.x * 64 + threadIdx.x;   // 0..12287
    const int i    = gid >> 1;                        // uint4 index 0..6143
    const int half = gid & 1;
    const int ct   = i / 768;
    const int rem  = i - ct * 768;
    const int kc   = rem >> 6;
    const int lane = rem & 63;
    const int q    = lane >> 4;
    const int col  = (ct << 4) | (lane & 15);
    const int m = col >> 2, d = col & 3;
    const int k = kc >> 2;
    const int n = (kc & 3) * 8 + q * 2 + half;
    float f[4];
#pragma unroll
    for (int x = 0; x < 4; ++x)
        f[x] = wp[(((k * 32 + n) * 4 + x) * 4 + d) * 32 + m] * 0.03125f;
    uint2 o;
    o.x = pk2(f[0], f[1]); o.y = pk2(f[2], f[3]);
    ws2[i * 2 + half] = o;
}

// LDS regions (single block copy = 55808 B -> 2 blocks/CU):
//  f32 stage:  byte(n,w,a) = n*1152 + w*64 + a*16, n=0..31, w=0..17, a=0..3
//              = 36864 B = EXACTLY 36 linear 1024-B DMA chunks (no pad lanes)
//  bf16 tile (VERIFIED layout): byte = n2*1184 + w*64 + a*16 (+8 for odd n)
#define XF32ROW 1152
#define XF32SZ  36864
#define XCHUNK  36
#define XBFOFF  36864
#define XSTRIDE_N2 1184

// ---------------------------------------------------------------------------
// R12: ONE pass; async f32 DMA staging + once-per-block LDS repack to bf16.
//  - staging: 36 global_load_lds chunks/slab, zero regs/VALU, prefetch of
//    slab s+1 issues before slab s K-loop, drained by end-of-slab barrier
//  - repack (conversion ONCE per element per block, off MFMA critical path):
//    per thread <=5 x {2 ds_read_b128 (n even/odd) + 4 pk2 + 1 ds_write_b128}
//    producing the byte-identical VERIFIED bf16 granule tile
//  - K-loop: pure bf16 LDS + MFMA (VERIFIED immediates), breg persistent
//  - stores: R10-verified 4x4 quad-lane transpose -> one dwordx4 each
// Grid (64,16), 256 thr, 2 slabs x 16 w.
// ---------------------------------------------------------------------------
__global__ __launch_bounds__(256, 2) void caps_mfma(
    const float* __restrict__ xp,   // [B][N][L][16] f32
    const uint4* __restrict__ ws,   // B frags
    const float* __restrict__ gp,   // [16]
    const float* __restrict__ bp,   // [16]
    float* __restrict__ out)        // [B][M][W][16]
{
    __shared__ __align__(16) unsigned char xs[XF32SZ + 16 * XSTRIDE_N2];

    const int tid  = threadIdx.x;
    const int wave = tid >> 6;
    const int lane = tid & 63;
    const int q    = lane >> 4;
    const int l15  = lane & 15;
    const int dL   = lane & 3;
    const int msub = (lane >> 2) & 3;
    const int b    = blockIdx.y;
    const int W0   = blockIdx.x * 32;  // 32-w super-tile (2 slabs x 16)
    const int ct0  = wave * 2;

    const float* xb = xp + (size_t)b * N_ * L_ * D_;

    // ---- DMA chunk geometry (slab-independent): ch = 4i+wave, 9/wave ----
    int srcf[9];   // float offset n*32768 + a*4  (gw*16 added per slab)
    int wrow[9];   // w row 0..17
#pragma unroll
    for (int i = 0; i < 9; ++i) {
        const int ch   = 4 * i + wave;            // 0..35, all valid
        const int dest = ch * 1024 + lane * 16;
        const int n    = dest / XF32ROW;
        const int rem  = dest - n * XF32ROW;
        wrow[i] = rem >> 6;
        srcf[i] = n * 32768 + ((rem >> 4) & 3) * 4;
    }

    auto issue = [&](int s) {
#pragma unroll
        for (int i = 0; i < 9; ++i) {
            int gw = W0 + s * 16 + wrow[i];
            if (gw > L_ - 1) gw = L_ - 1;          // halo clamp
            gload_lds16(xb + srcf[i] + gw * 16,
                        &xs[(4 * i + wave) * 1024 + lane * 16]);
        }
    };

    // ---- repack geometry: granule g = ((n2*18)+w)*4+a, 1152 over 256 thr --
    int  rdE[5], wrO[5];
    bool gval[5];
#pragma unroll
    for (int it = 0; it < 5; ++it) {
        const int g = it * 256 + tid;
        gval[it] = (it < 4) || (g < 1152);
        const int gg  = g < 1152 ? g : 1151;
        const int n2  = gg / 72;
        const int rem = gg - n2 * 72;
        const int w   = rem >> 2;
        const int a   = rem & 3;
        rdE[it] = (2 * n2) * XF32ROW + w * 64 + a * 16;   // even row read
        wrO[it] = n2 * XSTRIDE_N2 + w * 64 + a * 16;      // bf16 granule write
    }

    // f32 LDS -> VERIFIED bf16 granule {even 4 floats, odd 4 floats}
    auto repack = [&]() {
#pragma unroll
        for (int it = 0; it < 5; ++it) if (gval[it]) {
            const f32x4 e = *reinterpret_cast<const f32x4*>(&xs[rdE[it]]);
            const f32x4 o = *reinterpret_cast<const f32x4*>(&xs[rdE[it] + XF32ROW]);
            uint4 u;
            u.x = pk2(e[0], e[1]); u.y = pk2(e[2], e[3]);
            u.z = pk2(o[0], o[1]); u.w = pk2(o[2], o[3]);
            *reinterpret_cast<uint4*>(&xs[XBFOFF + wrO[it]]) = u;
        }
    };

    // ---- prologue: async slab-0 stage + persistent B frags + gamma/beta ----
    issue(0);

    uint4 breg[2][12];                             // 96 VGPR, block lifetime
#pragma unroll
    for (int cp = 0; cp < 2; ++cp)
#pragma unroll
        for (int kc = 0; kc < 12; ++kc)
            breg[cp][kc] = ws[(ct0 + cp) * 768 + kc * 64 + lane];

    float gmv[4], btv[4];
#pragma unroll
    for (int r = 0; r < 4; ++r) { gmv[r] = gp[r * 4 + dL]; btv[r] = bp[r * 4 + dL]; }

    __syncthreads();   // drains DMA -> slab-0 f32 image complete

    // per-lane bf16 A base (VERIFIED): offsets kn*4736 + k*64 + rt*256
    const unsigned char* ap =
        &xs[XBFOFF + q * XSTRIDE_N2 + (l15 >> 2) * 64 + (l15 & 3) * 16];

#pragma unroll
    for (int s = 0; s < 2; ++s) {
        repack();
        __syncthreads();                           // bf16 ready; f32 buf free

        if (s < 1) {
            issue(1);                              // async prefetch slab 1
            __builtin_amdgcn_sched_barrier(0);     // pin issue before K-loop
        }

        f32x4 acc[4][2];
#pragma unroll
        for (int rt = 0; rt < 4; ++rt)
#pragma unroll
            for (int cp = 0; cp < 2; ++cp)
                acc[rt][cp] = (f32x4){0.f, 0.f, 0.f, 0.f};

        // ---- K-loop: pure bf16 LDS + MFMA (VERIFIED layout/immediates) ----
#pragma unroll
        for (int kc = 0; kc < 12; ++kc) {
            const int k  = kc >> 2;
            const int kn = kc & 3;
            bf16x8 afr[4];
#pragma unroll
            for (int rt = 0; rt < 4; ++rt) {
                frag_cast c;
                c.u = *reinterpret_cast<const uint4*>(
                    ap + kn * 4736 + k * 64 + rt * 256);
                afr[rt] = c.f;
            }
#pragma unroll
            for (int cp = 0; cp < 2; ++cp) {
                frag_cast bc; bc.u = breg[cp][kc];
#pragma unroll
                for (int rt = 0; rt < 4; ++rt)
                    acc[rt][cp] = __builtin_amdgcn_mfma_f32_16x16x32_bf16(
                        afr[rt], bc.f, acc[rt][cp], 0, 0, 0);
            }
        }

        // ---- fused LayerNorm (VERIFIED) + 4x4 quad transpose + dwordx4 ----
#pragma unroll
        for (int rt = 0; rt < 4; ++rt) {
            const int wv = W0 + s * 16 + rt * 4 + q;
#pragma unroll
            for (int cp = 0; cp < 2; ++cp) {
                const f32x4 v = acc[rt][cp];
                float ss = v[0] + v[1] + v[2] + v[3];
                float sq = v[0]*v[0] + v[1]*v[1] + v[2]*v[2] + v[3]*v[3];
                ss += __shfl_xor(ss, 1); ss += __shfl_xor(ss, 2);
                sq += __shfl_xor(sq, 1); sq += __shfl_xor(sq, 2);
                const float mu   = ss * (1.f / 16.f);
                const float var  = sq * (1.f / 16.f) - mu * mu;
                const float rstd = rsqrtf(var + 1e-5f);
                float y[4];
#pragma unroll
                for (int r = 0; r < 4; ++r)
                    y[r] = gmv[r] * (v[r] - mu) * rstd + btv[r];
                // 4x4 transpose over (dL, r): lane dL -> dout 4dL..4dL+3
#pragma unroll
                for (int mm = 1; mm <= 2; mm <<= 1) {
                    float p[4];
#pragma unroll
                    for (int r = 0; r < 4; ++r) p[r] = __shfl_xor(y[r], mm);
#pragma unroll
                    for (int r = 0; r < 4; ++r)
                        y[r] = ((dL ^ r) & mm) ? p[r ^ mm] : y[r];
                }
                if (wv < W_) {
                    const int m = (ct0 + cp) * 4 + msub;
                    float4* op = (float4*)(out +
                        ((size_t)(b * M_ + m) * W_ + wv) * D_ + dL * 4);
                    *op = make_float4(y[0], y[1], y[2], y[3]);
                }
            }
        }

        if (s < 1) __syncthreads();  // drains DMA (slab-1 f32 image) +
                                     // protects bf16 buf from next repack
    }
}

extern "C" void kernel_launch(void* const* d_in, const int* in_sizes, int n_in,
                              void* d_out, int out_size, void* d_ws, size_t ws_size,
                              hipStream_t stream) {
    const float* x  = (const float*)d_in[0];
    const float* w  = (const float*)d_in[1];
    const float* g  = (const float*)d_in[2];
    const float* be = (const float*)d_in[3];
    float* out = (float*)d_out;

    caps_setup<<<192, 64, 0, stream>>>(w, (uint2*)d_ws);
    caps_mfma<<<dim3(64, 16), 256, 0, stream>>>(
        x, (const uint4*)d_ws, g, be, out);
}